// Round 5
// baseline (216.358 us; speedup 1.0000x reference)
//
#include <hip/hip_runtime.h>
#include <math.h>

// x, x_r: (1, 3, 32, 512, 512) fp32. size=64 -> hc=wc=32, nh=nw=16.
// P[t,ph,pw] = mean over (c=3, 32x32) of |x - x_r|/2   (3072 elems/patch)
// out = log( mean_t( max(0, max_{ph,pw} P) ) )  -- scalar fp32.
//
// Round 13: global_load_lds DMA staging (last untested read path).
//   Ladder: cached loads ~72us (L1 miss-slot cap), nt loads ~55-58us,
//   occupancy x2 (R9) null, 24-deep register pipeline (R11) null.
//   Wave-level MLP math shows in-flight bytes were never the limiter
//   (1 KB per wave-load; even 2/wave x 16 waves covers ~75 TB/s at 1us
//   latency) -> cap is the per-CU read-RETURN path (~6 B/cy/CU).
//   global_load_lds bypasses the VGPR writeback entirely (DMA into LDS),
//   a genuinely different return route. Same R8 partition: block b owns
//   3 contiguous 32 KB chunks per input; 12 subchunk-pairs of 8 KB,
//   double-buffered (lA/lC x2 = 32 KB LDS). Raw s_barrier + counted
//   vmcnt(4) so staging never drains (a __syncthreads would emit
//   vmcnt(0) and serialize the DMA queue). Bins: f4 index i = s*512 +
//   {tid, 256+tid}, i mod 128 = tid mod 128 -> bin=(tid&127)>>3 const;
//   chunk k = s>>2 (compile-time in the unrolled loop).
// Kernel 2: unchanged R8 finalize (measured ~4 us).

typedef float vf4 __attribute__((ext_vector_type(4)));

#define AS1(p) ((const __attribute__((address_space(1))) void*)(p))
#define AS3(p) ((__attribute__((address_space(3))) void*)(p))

__global__ __launch_bounds__(256, 4) void patch_sum_kernel(
    const float* __restrict__ x, const float* __restrict__ xr,
    float* __restrict__ part) {
  __shared__ vf4 lA[2][512];          // 2 x 8 KB
  __shared__ vf4 lC[2][512];          // 2 x 8 KB
  const int b   = blockIdx.x;         // 0..1023
  const int tid = threadIdx.x;        // 0..255
  const size_t base = (size_t)b * 98304;   // 96 KB per input per block
  const char* __restrict__ ga = (const char*)x  + base + (size_t)tid * 16;
  const char* __restrict__ gc = (const char*)xr + base + (size_t)tid * 16;
  const int wv = (tid >> 6) << 6;     // wave base in vf4 units (64 vf4 = 1 KB)

  // stage subchunk s (8 KB per input) into buffer p: 2 calls per input,
  // each call = wave-uniform LDS base + lane*16, covering 4 KB across 4 waves.
  auto stage = [&](int s, int p) {
    const size_t off = (size_t)s * 8192;
    __builtin_amdgcn_global_load_lds(AS1(ga + off),        AS3(&lA[p][wv]),        16, 0, 0);
    __builtin_amdgcn_global_load_lds(AS1(ga + off + 4096), AS3(&lA[p][256 + wv]),  16, 0, 0);
    __builtin_amdgcn_global_load_lds(AS1(gc + off),        AS3(&lC[p][wv]),        16, 0, 0);
    __builtin_amdgcn_global_load_lds(AS1(gc + off + 4096), AS3(&lC[p][256 + wv]),  16, 0, 0);
  };

  stage(0, 0);                        // 4 vm ops
  stage(1, 1);                        // 8 outstanding
  float acc[3] = {0.f, 0.f, 0.f};

#pragma unroll
  for (int s = 0; s < 12; ++s) {
    const int p = s & 1;
    if (s < 11) {
      asm volatile("s_waitcnt vmcnt(4)" ::: "memory");   // stage(s) landed
    } else {
      asm volatile("s_waitcnt vmcnt(0)" ::: "memory");   // last: drain
    }
    __builtin_amdgcn_s_barrier();     // all waves' portions of buf p landed
    vf4 A0 = lA[p][tid];       vf4 C0 = lC[p][tid];
    vf4 A1 = lA[p][256 + tid]; vf4 C1 = lC[p][256 + tid];
    float d = fabsf(A0.x - C0.x) + fabsf(A0.y - C0.y)
            + fabsf(A0.z - C0.z) + fabsf(A0.w - C0.w)
            + fabsf(A1.x - C1.x) + fabsf(A1.y - C1.y)
            + fabsf(A1.z - C1.z) + fabsf(A1.w - C1.w);
    acc[s >> 2] += d;                 // chunk k = s>>2, compile-time
    __builtin_amdgcn_s_barrier();     // all waves done reading buf p
    if (s + 2 < 12) stage(s + 2, p);  // overwrite buf p for subchunk s+2
  }

  float acc0 = acc[0], acc1 = acc[1], acc2 = acc[2];
  // 8-lane group reduce for each chunk accumulator (bin = (tid&127)>>3).
#pragma unroll
  for (int o = 4; o > 0; o >>= 1) {
    acc0 += __shfl_down(acc0, o, 8);
    acc1 += __shfl_down(acc1, o, 8);
    acc2 += __shfl_down(acc2, o, 8);
  }
  __shared__ float sred[3][32];
  if ((tid & 7) == 0) {
    int m = tid >> 3;                 // 0..31 ; bin = m & 15
    sred[0][m] = acc0;
    sred[1][m] = acc1;
    sred[2][m] = acc2;
  }
  __syncthreads();
  if (tid < 48) {
    int k = tid >> 4;                 // which chunk of the 3
    int bin = tid & 15;               // pw
    part[(size_t)(b * 3 + k) * 16 + bin] = sred[k][bin] + sred[k][bin + 16];
  }
}

__global__ __launch_bounds__(1024) void finalize_kernel(
    const float* __restrict__ part, float* __restrict__ out) {
  const int tid = threadIdx.x;
  const int t = tid >> 5;             // 0..31
  const int j = tid & 31;
  float m = -1e30f;
#pragma unroll
  for (int k = 0; k < 8; ++k) {
    int p = t * 256 + j + 32 * k;     // patch id within frame t
    int ph = (p >> 4) & 15;
    int pw = p & 15;
    float v = 0.f;
#pragma unroll
    for (int ch = 0; ch < 3; ++ch) {
#pragma unroll
      for (int half = 0; half < 2; ++half) {
        int idx = ((ch << 10) + (t << 5) + (ph << 1) + half) * 16 + pw;
        v += part[idx];
      }
    }
    m = fmaxf(m, v);
  }
#pragma unroll
  for (int o = 16; o > 0; o >>= 1) m = fmaxf(m, __shfl_down(m, o, 32));
  __shared__ float s[32];
  if (j == 0) s[t] = fmaxf(m * (0.5f / 3072.0f), 0.f);  // scale + clamp at 0
  __syncthreads();
  if (tid < 32) {
    float v = s[tid];
#pragma unroll
    for (int o = 16; o > 0; o >>= 1) v += __shfl_down(v, o, 32);
    if (tid == 0) out[0] = logf(v * (1.0f / 32.0f));
  }
}

extern "C" void kernel_launch(void* const* d_in, const int* in_sizes, int n_in,
                              void* d_out, int out_size, void* d_ws, size_t ws_size,
                              hipStream_t stream) {
  const float* x  = (const float*)d_in[0];
  const float* xr = (const float*)d_in[1];
  float* part = (float*)d_ws;        // 3072*16 floats = 192 KB scratch
  float* out  = (float*)d_out;

  patch_sum_kernel<<<1024, 256, 0, stream>>>(x, xr, part);
  finalize_kernel<<<1, 1024, 0, stream>>>(part, out);
}

// Round 6
// 208.321 us; speedup vs baseline: 1.0386x; 1.0386x over previous
//
#include <hip/hip_runtime.h>
#include <math.h>

// x, x_r: (1, 3, 32, 512, 512) fp32. size=64 -> hc=wc=32, nh=nw=16.
// P[t,ph,pw] = mean over (c=3, 32x32) of |x - x_r|/2   (3072 elems/patch)
// out = log( mean_t( max(0, max_{ph,pw} P) ) )  -- scalar fp32.
//
// Round 14: HYBRID read paths. Measured read ladder: cached 2.8 TB/s,
//   nt 3.7, DMA-to-LDS 2.7; occupancy x2 null; 24-deep reg MLP null.
//   Last discriminating test: nt-vector path and LDS-DMA path CONCURRENTLY.
//   If their queues are independent, rates sum (~6 TB/s); if the cap is
//   shared (L2 fill / fabric read-return), hybrid lands at 3.7 -> declare
//   structural roofline. Block b (1024 x 256 thr) owns 3 x 32 KB chunks
//   per input: chunks 0,1 via nt loads (R8 exact shape), chunk 2 via
//   global_load_lds in 4 x 8 KB subchunks, double-buffered (32 KB LDS),
//   staged BEFORE the nt loop so DMA flows under the nt stream; counted
//   vmcnt(4) + raw barriers (R13-verified pattern). part[] layout and
//   bins unchanged: all f4 offsets = tid mod 128 -> bin=(tid&127)>>3.
// Kernel 2: unchanged R8 finalize (measured ~4 us).

typedef float vf4 __attribute__((ext_vector_type(4)));

#define AS1(p) ((const __attribute__((address_space(1))) void*)(p))
#define AS3(p) ((__attribute__((address_space(3))) void*)(p))

__global__ __launch_bounds__(256, 4) void patch_sum_kernel(
    const float* __restrict__ x, const float* __restrict__ xr,
    float* __restrict__ part) {
  __shared__ vf4 lA[2][512];          // 2 x 8 KB
  __shared__ vf4 lC[2][512];          // 2 x 8 KB
  const int b   = blockIdx.x;         // 0..1023
  const int tid = threadIdx.x;        // 0..255
  const size_t base4 = (size_t)b * 6144;         // f4 units, 96 KB/input
  const vf4* __restrict__ a4 = (const vf4*)x  + base4;
  const vf4* __restrict__ c4 = (const vf4*)xr + base4;
  // DMA source: chunk 2 = bytes [65536, 98304) of the block's region
  const char* __restrict__ ga = (const char*)x  + base4 * 16 + 65536 + (size_t)tid * 16;
  const char* __restrict__ gc = (const char*)xr + base4 * 16 + 65536 + (size_t)tid * 16;
  const int wv = tid & 192;           // wave base in vf4 units

  // stage subchunk s (8 KB per input) into buffer p (4 DMA wave-ops)
  auto stage = [&](int s, int p) {
    const size_t off = (size_t)s * 8192;
    __builtin_amdgcn_global_load_lds(AS1(ga + off),        AS3(&lA[p][wv]),        16, 0, 0);
    __builtin_amdgcn_global_load_lds(AS1(ga + off + 4096), AS3(&lA[p][256 + wv]),  16, 0, 0);
    __builtin_amdgcn_global_load_lds(AS1(gc + off),        AS3(&lC[p][wv]),        16, 0, 0);
    __builtin_amdgcn_global_load_lds(AS1(gc + off + 4096), AS3(&lC[p][256 + wv]),  16, 0, 0);
  };

  stage(0, 0);                        // 4 DMA ops
  stage(1, 1);                        // 8 outstanding
  asm volatile("" ::: "memory");      // pin issue order: DMA first

  // ---- chunks 0,1: nt vector stream (overlaps the DMA in flight) ----
  float acc0 = 0.f, acc1 = 0.f, acc2 = 0.f;
#pragma unroll
  for (int i = 0; i < 8; ++i) {
    int o = i * 256 + tid;
    vf4 A0 = __builtin_nontemporal_load(&a4[o]);
    vf4 C0 = __builtin_nontemporal_load(&c4[o]);
    vf4 A1 = __builtin_nontemporal_load(&a4[2048 + o]);
    vf4 C1 = __builtin_nontemporal_load(&c4[2048 + o]);
    acc0 += fabsf(A0.x - C0.x) + fabsf(A0.y - C0.y)
          + fabsf(A0.z - C0.z) + fabsf(A0.w - C0.w);
    acc1 += fabsf(A1.x - C1.x) + fabsf(A1.y - C1.y)
          + fabsf(A1.z - C1.z) + fabsf(A1.w - C1.w);
  }

  // ---- chunk 2: consume DMA-staged subchunks (dbuf, counted vmcnt) ----
#pragma unroll
  for (int s = 0; s < 4; ++s) {
    const int p = s & 1;
    if (s < 3) {
      asm volatile("s_waitcnt vmcnt(4)" ::: "memory");   // stage(s) landed
    } else {
      asm volatile("s_waitcnt vmcnt(0)" ::: "memory");   // last: drain
    }
    __builtin_amdgcn_s_barrier();     // all waves' portions of buf p landed
    vf4 A0 = lA[p][tid];       vf4 C0 = lC[p][tid];
    vf4 A1 = lA[p][256 + tid]; vf4 C1 = lC[p][256 + tid];
    acc2 += fabsf(A0.x - C0.x) + fabsf(A0.y - C0.y)
          + fabsf(A0.z - C0.z) + fabsf(A0.w - C0.w)
          + fabsf(A1.x - C1.x) + fabsf(A1.y - C1.y)
          + fabsf(A1.z - C1.z) + fabsf(A1.w - C1.w);
    __builtin_amdgcn_s_barrier();     // all waves done reading buf p
    if (s + 2 < 4) stage(s + 2, p);   // overwrite buf p for subchunk s+2
  }

  // 8-lane group reduce for each chunk accumulator (bin = (tid&127)>>3).
#pragma unroll
  for (int o = 4; o > 0; o >>= 1) {
    acc0 += __shfl_down(acc0, o, 8);
    acc1 += __shfl_down(acc1, o, 8);
    acc2 += __shfl_down(acc2, o, 8);
  }
  __shared__ float sred[3][32];
  if ((tid & 7) == 0) {
    int m = tid >> 3;                 // 0..31 ; bin = m & 15
    sred[0][m] = acc0;
    sred[1][m] = acc1;
    sred[2][m] = acc2;
  }
  __syncthreads();
  if (tid < 48) {
    int k = tid >> 4;                 // which chunk of the 3
    int bin = tid & 15;               // pw
    part[(size_t)(b * 3 + k) * 16 + bin] = sred[k][bin] + sred[k][bin + 16];
  }
}

__global__ __launch_bounds__(1024) void finalize_kernel(
    const float* __restrict__ part, float* __restrict__ out) {
  const int tid = threadIdx.x;
  const int t = tid >> 5;             // 0..31
  const int j = tid & 31;
  float m = -1e30f;
#pragma unroll
  for (int k = 0; k < 8; ++k) {
    int p = t * 256 + j + 32 * k;     // patch id within frame t
    int ph = (p >> 4) & 15;
    int pw = p & 15;
    float v = 0.f;
#pragma unroll
    for (int ch = 0; ch < 3; ++ch) {
#pragma unroll
      for (int half = 0; half < 2; ++half) {
        int idx = ((ch << 10) + (t << 5) + (ph << 1) + half) * 16 + pw;
        v += part[idx];
      }
    }
    m = fmaxf(m, v);
  }
#pragma unroll
  for (int o = 16; o > 0; o >>= 1) m = fmaxf(m, __shfl_down(m, o, 32));
  __shared__ float s[32];
  if (j == 0) s[t] = fmaxf(m * (0.5f / 3072.0f), 0.f);  // scale + clamp at 0
  __syncthreads();
  if (tid < 32) {
    float v = s[tid];
#pragma unroll
    for (int o = 16; o > 0; o >>= 1) v += __shfl_down(v, o, 32);
    if (tid == 0) out[0] = logf(v * (1.0f / 32.0f));
  }
}

extern "C" void kernel_launch(void* const* d_in, const int* in_sizes, int n_in,
                              void* d_out, int out_size, void* d_ws, size_t ws_size,
                              hipStream_t stream) {
  const float* x  = (const float*)d_in[0];
  const float* xr = (const float*)d_in[1];
  float* part = (float*)d_ws;        // 3072*16 floats = 192 KB scratch
  float* out  = (float*)d_out;

  patch_sum_kernel<<<1024, 256, 0, stream>>>(x, xr, part);
  finalize_kernel<<<1, 1024, 0, stream>>>(part, out);
}

// Round 7
// 193.984 us; speedup vs baseline: 1.1153x; 1.0739x over previous
//
#include <hip/hip_runtime.h>
#include <math.h>

// x, x_r: (1, 3, 32, 512, 512) fp32. size=64 -> hc=wc=32, nh=nw=16.
// P[t,ph,pw] = mean over (c=3, 32x32) of |x - x_r|/2   (3072 elems/patch)
// out = log( mean_t( max(0, max_{ph,pw} P) ) )  -- scalar fp32.
//
// FINAL (revert to measured-best R8 structure; 194.0/195.6 us).
// Read-path cap ladder measured this session (patch_sum, 201 MB read):
//   cached 2.8 TB/s | nt 3.7 (best) | DMA-to-LDS 2.7 | nt+DMA hybrid 3.7
//   (no summing) | 2x occupancy null | 24-deep reg pipeline null.
// Concurrent paths not summing + L3-resident half arriving at the same
//   rate => shared L2-fill/fabric read-return cap ~3.7 TB/s. Structural
//   roofline for this op: 201 MB / 3.7 TB/s ~= 55 us + ~4 us finalize;
//   remainder of the bench window is harness poison fills (~59 us each).
//
// Structure: chunk = contiguous 2048 f4 (16 rows x 512 cols of one
//   (ch,t) frame); 3072 chunks. 1024 blocks x 256 thr; block b streams
//   chunks 3b..3b+2 (96 KB contiguous per input): each inner iter issues
//   6 independent nt loads into 3 independent accumulators -> continuous
//   issue, no drain. pw bin = (tid&127)>>3 constant per thread -> scalar
//   accumulators.
// Kernel 2: one 1024-thread block: sum 6 chunk-contributions per patch,
//   per-t max, clamp, mean, log (measured ~4 us).

typedef float vf4 __attribute__((ext_vector_type(4)));

__global__ __launch_bounds__(256) void patch_sum_kernel(
    const float* __restrict__ x, const float* __restrict__ xr,
    float* __restrict__ part) {
  const int b   = blockIdx.x;        // 0..1023
  const int tid = threadIdx.x;
  const size_t base4 = (size_t)b * 3 * 2048;
  const vf4* __restrict__ a4 = (const vf4*)x  + base4;
  const vf4* __restrict__ c4 = (const vf4*)xr + base4;

  float acc0 = 0.f, acc1 = 0.f, acc2 = 0.f;
#pragma unroll
  for (int i = 0; i < 8; ++i) {
    int o = i * 256 + tid;
    vf4 a0 = __builtin_nontemporal_load(&a4[o]);
    vf4 c0 = __builtin_nontemporal_load(&c4[o]);
    vf4 a1 = __builtin_nontemporal_load(&a4[2048 + o]);
    vf4 c1 = __builtin_nontemporal_load(&c4[2048 + o]);
    vf4 a2 = __builtin_nontemporal_load(&a4[4096 + o]);
    vf4 c2 = __builtin_nontemporal_load(&c4[4096 + o]);
    acc0 += fabsf(a0.x - c0.x) + fabsf(a0.y - c0.y)
          + fabsf(a0.z - c0.z) + fabsf(a0.w - c0.w);
    acc1 += fabsf(a1.x - c1.x) + fabsf(a1.y - c1.y)
          + fabsf(a1.z - c1.z) + fabsf(a1.w - c1.w);
    acc2 += fabsf(a2.x - c2.x) + fabsf(a2.y - c2.y)
          + fabsf(a2.z - c2.z) + fabsf(a2.w - c2.w);
  }

  // 8-lane group reduce for each chunk accumulator (bin = (tid&127)>>3).
#pragma unroll
  for (int o = 4; o > 0; o >>= 1) {
    acc0 += __shfl_down(acc0, o, 8);
    acc1 += __shfl_down(acc1, o, 8);
    acc2 += __shfl_down(acc2, o, 8);
  }
  __shared__ float s[3][32];
  if ((tid & 7) == 0) {
    int m = tid >> 3;                // 0..31 ; bin = m & 15
    s[0][m] = acc0;
    s[1][m] = acc1;
    s[2][m] = acc2;
  }
  __syncthreads();
  if (tid < 48) {
    int k = tid >> 4;                // which chunk of the 3
    int bin = tid & 15;              // pw
    part[(size_t)(b * 3 + k) * 16 + bin] = s[k][bin] + s[k][bin + 16];
  }
}

__global__ __launch_bounds__(1024) void finalize_kernel(
    const float* __restrict__ part, float* __restrict__ out) {
  const int tid = threadIdx.x;
  const int t = tid >> 5;             // 0..31
  const int j = tid & 31;
  float m = -1e30f;
#pragma unroll
  for (int k = 0; k < 8; ++k) {
    int p = t * 256 + j + 32 * k;     // patch id within frame t
    int ph = (p >> 4) & 15;
    int pw = p & 15;
    float v = 0.f;
#pragma unroll
    for (int ch = 0; ch < 3; ++ch) {
#pragma unroll
      for (int half = 0; half < 2; ++half) {
        int idx = ((ch << 10) + (t << 5) + (ph << 1) + half) * 16 + pw;
        v += part[idx];
      }
    }
    m = fmaxf(m, v);
  }
#pragma unroll
  for (int o = 16; o > 0; o >>= 1) m = fmaxf(m, __shfl_down(m, o, 32));
  __shared__ float s[32];
  if (j == 0) s[t] = fmaxf(m * (0.5f / 3072.0f), 0.f);  // scale + clamp at 0
  __syncthreads();
  if (tid < 32) {
    float v = s[tid];
#pragma unroll
    for (int o = 16; o > 0; o >>= 1) v += __shfl_down(v, o, 32);
    if (tid == 0) out[0] = logf(v * (1.0f / 32.0f));
  }
}

extern "C" void kernel_launch(void* const* d_in, const int* in_sizes, int n_in,
                              void* d_out, int out_size, void* d_ws, size_t ws_size,
                              hipStream_t stream) {
  const float* x  = (const float*)d_in[0];
  const float* xr = (const float*)d_in[1];
  float* part = (float*)d_ws;        // 3072*16 floats = 192 KB scratch
  float* out  = (float*)d_out;

  patch_sum_kernel<<<1024, 256, 0, stream>>>(x, xr, part);
  finalize_kernel<<<1, 1024, 0, stream>>>(part, out);
}